// Round 2
// baseline (1345.726 us; speedup 1.0000x reference)
//
#include <hip/hip_runtime.h>
#include <math.h>

// Problem constants (from reference)
#define Bn   2
#define Ln   1024
#define DIMn 256
#define DIn  512
#define DSn  64
#define DTRn 16
#define Kn   4
#define HIDn 1024
#define NCH  8          // scan chunks
#define CL   128        // chunk length (NCH*CL == Ln)
#define NREC 262144     // b*k*d*s recurrences = 2*4*512*64

__device__ __forceinline__ float silu_f(float x) { return x / (1.f + __expf(-x)); }
__device__ __forceinline__ float softplus_f(float x) { return (x > 20.f) ? x : log1pf(__expf(x)); }
__device__ __forceinline__ float gelu_f(float x) {
    float x3 = x * x * x;
    float t = tanhf(0.7978845608028654f * (x + 0.044715f * x3));
    return 0.5f * x * (1.f + t);
}
// scan-direction index permutation: xs[b,k,l,:] = xic[b, permidx(k,l), :]
__device__ __forceinline__ int permidx(int k, int l) {
    switch (k & 3) {
        case 0:  return l;
        case 1:  return ((l & 31) << 5) | (l >> 5);
        case 2:  return (Ln - 1) - l;
        default: { int j = (Ln - 1) - l; return ((j & 31) << 5) | (j >> 5); }
    }
}

// ---------------------------------------------------------------- k_mod
__global__ __launch_bounds__(256) void k_mod(const float* __restrict__ c,
                                             const float* __restrict__ W,
                                             const float* __restrict__ bias,
                                             float* __restrict__ mod) {
    __shared__ float sc[DIMn];
    int b = blockIdx.y;
    int j = blockIdx.x * 256 + threadIdx.x;
    sc[threadIdx.x] = silu_f(c[b * DIMn + threadIdx.x]);
    __syncthreads();
    float acc = bias[j];
#pragma unroll 4
    for (int r = 0; r < DIMn; r++) acc = fmaf(sc[r], W[r * 1536 + j], acc);
    mod[b * 1536 + j] = acc;
}

// ---------------------------------------------------------------- k_ln_mod
__global__ __launch_bounds__(256) void k_ln_mod(const float* __restrict__ x,
                                                const float* __restrict__ mod,
                                                int sh_ofs, int sc_ofs,
                                                float* __restrict__ out) {
    int b = blockIdx.y, l = blockIdx.x, d = threadIdx.x;
    float v = x[((size_t)(b << 10) + l) * DIMn + d];
    float s1 = v, s2 = v * v;
#pragma unroll
    for (int o = 32; o > 0; o >>= 1) { s1 += __shfl_xor(s1, o); s2 += __shfl_xor(s2, o); }
    __shared__ float red[8];
    int wid = threadIdx.x >> 6, lane = threadIdx.x & 63;
    if (lane == 0) { red[wid * 2] = s1; red[wid * 2 + 1] = s2; }
    __syncthreads();
    s1 = red[0] + red[2] + red[4] + red[6];
    s2 = red[1] + red[3] + red[5] + red[7];
    float mu  = s1 * (1.f / DIMn);
    float var = s2 * (1.f / DIMn) - mu * mu;
    float r   = rsqrtf(var + 1e-6f);
    float sh  = mod[b * 1536 + sh_ofs + d];
    float scv = mod[b * 1536 + sc_ofs + d];
    out[((size_t)(b << 10) + l) * DIMn + d] = (v - mu) * r * (1.f + scv) + sh;
}

// ---------------------------------------------------------------- gemm64
// EPI 0: +bias   EPI 1: gelu(+bias)   EPI 2: resid + mod[b,gofs+n]*(+bias)
template <int EPI>
__global__ __launch_bounds__(256) void gemm64(const float* __restrict__ A,
                                              const float* __restrict__ W,
                                              const float* __restrict__ bias,
                                              float* __restrict__ out,
                                              int N, int Kd,
                                              const float* __restrict__ resid,
                                              const float* __restrict__ mod,
                                              int gofs) {
    __shared__ float As[16][68];
    __shared__ float Bs[16][68];
    int row0 = blockIdx.y << 6, col0 = blockIdx.x << 6;
    int tx = threadIdx.x & 15, ty = threadIdx.x >> 4;
    float acc[4][4] = {};
    for (int k0 = 0; k0 < Kd; k0 += 16) {
#pragma unroll
        for (int i = 0; i < 4; i++) {
            int idx = threadIdx.x + i * 256;
            int m = idx >> 4, kk = idx & 15;
            As[kk][m] = A[(size_t)(row0 + m) * Kd + k0 + kk];
            int n = idx & 63, k2 = idx >> 6;
            int col = col0 + n;
            Bs[k2][n] = (col < N) ? W[(size_t)(k0 + k2) * N + col] : 0.f;
        }
        __syncthreads();
#pragma unroll
        for (int kk = 0; kk < 16; kk++) {
            float a[4], bb[4];
#pragma unroll
            for (int i = 0; i < 4; i++) a[i] = As[kk][ty * 4 + i];
#pragma unroll
            for (int j = 0; j < 4; j++) bb[j] = Bs[kk][tx * 4 + j];
#pragma unroll
            for (int i = 0; i < 4; i++)
#pragma unroll
                for (int j = 0; j < 4; j++) acc[i][j] = fmaf(a[i], bb[j], acc[i][j]);
        }
        __syncthreads();
    }
#pragma unroll
    for (int i = 0; i < 4; i++) {
        int row = row0 + ty * 4 + i;
#pragma unroll
        for (int j = 0; j < 4; j++) {
            int col = col0 + tx * 4 + j;
            if (col < N) {
                float v = acc[i][j] + bias[col];
                if (EPI == 1) v = gelu_f(v);
                if (EPI == 2) v = resid[(size_t)row * N + col] +
                                  mod[(row >> 10) * 1536 + gofs + col] * v;
                out[(size_t)row * N + col] = v;
            }
        }
    }
}

// ---------------------------------------------------------------- gemm_xdbl
__global__ __launch_bounds__(256) void gemm_xdbl(const float* __restrict__ xic,
                                                 const float* __restrict__ Wx,
                                                 float* __restrict__ xdbl) {
    __shared__ float As[16][68];
    __shared__ float Bs[16][68];
    int bk = blockIdx.z;              // b*4+k
    int b = bk >> 2, k = bk & 3;
    int row0 = blockIdx.y << 6, col0 = blockIdx.x << 6;
    const float* Ab = xic + (size_t)b * Ln * DIn;
    const float* Wb = Wx + (size_t)k * DIn * 144;
    float* ob = xdbl + (size_t)bk * Ln * 144;
    int tx = threadIdx.x & 15, ty = threadIdx.x >> 4;
    float acc[4][4] = {};
    for (int k0 = 0; k0 < DIn; k0 += 16) {
#pragma unroll
        for (int i = 0; i < 4; i++) {
            int idx = threadIdx.x + i * 256;
            int m = idx >> 4, kk = idx & 15;
            As[kk][m] = Ab[(size_t)permidx(k, row0 + m) * DIn + k0 + kk];
            int n = idx & 63, k2 = idx >> 6;
            int col = col0 + n;
            Bs[k2][n] = (col < 144) ? Wb[(size_t)(k0 + k2) * 144 + col] : 0.f;
        }
        __syncthreads();
#pragma unroll
        for (int kk = 0; kk < 16; kk++) {
            float a[4], bb[4];
#pragma unroll
            for (int i = 0; i < 4; i++) a[i] = As[kk][ty * 4 + i];
#pragma unroll
            for (int j = 0; j < 4; j++) bb[j] = Bs[kk][tx * 4 + j];
#pragma unroll
            for (int i = 0; i < 4; i++)
#pragma unroll
                for (int j = 0; j < 4; j++) acc[i][j] = fmaf(a[i], bb[j], acc[i][j]);
        }
        __syncthreads();
    }
#pragma unroll
    for (int i = 0; i < 4; i++) {
        int row = row0 + ty * 4 + i;
#pragma unroll
        for (int j = 0; j < 4; j++) {
            int col = col0 + tx * 4 + j;
            if (col < 144) ob[(size_t)row * 144 + col] = acc[i][j];
        }
    }
}

// ---------------------------------------------------------------- k_conv
__global__ __launch_bounds__(256) void k_conv(const float* __restrict__ xz,
                                              const float* __restrict__ cw,
                                              const float* __restrict__ cb,
                                              float* __restrict__ xic) {
    int idx = blockIdx.x * 256 + threadIdx.x;   // b*L*512 + l*512 + d
    int d = idx & 511;
    int l = (idx >> 9) & 1023;
    int b = idx >> 19;
    int hh = l >> 5, ww = l & 31;
    float acc = cb[d];
#pragma unroll
    for (int ky = 0; ky < 3; ky++) {
        int y = hh + ky - 1;
        if ((unsigned)y >= 32u) continue;
#pragma unroll
        for (int kx = 0; kx < 3; kx++) {
            int xw = ww + kx - 1;
            if ((unsigned)xw >= 32u) continue;
            acc = fmaf(cw[(ky * 3 + kx) * DIn + d],
                       xz[((size_t)(b << 10) + (y << 5) + xw) * 1024 + d], acc);
        }
    }
    xic[idx] = silu_f(acc);
}

// ---------------------------------------------------------------- k_dt
// dtt[b,k,d,l] = softplus(xdbl[b,k,l,0:16] @ W_dt[k] + dt_bias[k,d]) — transposed store
__global__ __launch_bounds__(256) void k_dt(const float* __restrict__ xdbl,
                                            const float* __restrict__ W_dt,
                                            const float* __restrict__ dt_bias,
                                            float* __restrict__ dtt) {
    __shared__ float Wd[16][64];
    __shared__ float Ar[64][16];
    __shared__ float tile[64][65];
    int bk = blockIdx.z;   // b*4+k
    int k = bk & 3;
    int l0 = blockIdx.x << 6, d0 = blockIdx.y << 6;
    const float* xb = xdbl + (size_t)bk * Ln * 144;
#pragma unroll
    for (int i = 0; i < 4; i++) {
        int idx = threadIdx.x + i * 256;
        int r = idx >> 6, dl = idx & 63;
        Wd[r][dl] = W_dt[(size_t)(k * 16 + r) * DIn + d0 + dl];
        int lr = idx >> 4, r2 = idx & 15;
        Ar[lr][r2] = xb[(size_t)(l0 + lr) * 144 + r2];
    }
    __syncthreads();
    {
        int dl = threadIdx.x & 63, lb = threadIdx.x >> 6;
        float bias = dt_bias[k * DIn + d0 + dl];
#pragma unroll
        for (int i = 0; i < 16; i++) {
            int lr = lb * 16 + i;
            float acc = bias;
#pragma unroll
            for (int r = 0; r < 16; r++) acc = fmaf(Ar[lr][r], Wd[r][dl], acc);
            tile[lr][dl] = softplus_f(acc);
        }
    }
    __syncthreads();
    {
        int ll = threadIdx.x & 63, db = threadIdx.x >> 6;
        float* ob = dtt + ((size_t)bk * DIn + d0) * Ln + l0;
#pragma unroll
        for (int i = 0; i < 16; i++) {
            int dl2 = db * 16 + i;
            ob[(size_t)dl2 * Ln + ll] = tile[ll][dl2];
        }
    }
}

// ---------------------------------------------------------------- k_scan1
// Per (b,k,d,chunk) wave, lanes = states: chunk decay product P and
// zero-input endpoint E. No reductions.
__global__ __launch_bounds__(256) void k_scan1(const float* __restrict__ dtt,
                                               const float* __restrict__ xdbl,
                                               const float* __restrict__ xic,
                                               const float* __restrict__ A_log,
                                               float* __restrict__ Pbuf,
                                               float* __restrict__ Ebuf) {
    int wid = threadIdx.x >> 6, lane = threadIdx.x & 63;
    int w = blockIdx.x * 4 + wid;          // [0, 32768)
    int d = w & 511;
    int bk = (w >> 9) & 7;
    int ch = w >> 12;                      // [0, NCH)
    int k = bk & 3;
    int g = bk * 512 + d;
    const float* dtp = dtt + (size_t)g * Ln;
    const float* xdb = xdbl + (size_t)bk * Ln * 144;
    const float* xcb = xic + (size_t)(bk >> 2) * Ln * DIn + d;
    float Aln = -__expf(A_log[(size_t)(k * DIn + d) * DSn + lane]);
    float P = 1.f, E = 0.f;
    int l0 = ch * CL;
#pragma unroll 4
    for (int j = 0; j < CL; j++) {
        int l = l0 + j;
        float dt = dtp[l];
        float u  = xcb[(size_t)permidx(k, l) * DIn];
        float Bv = xdb[l * 144 + 16 + lane];
        float dA = __expf(dt * Aln);
        P *= dA;
        E = fmaf(E, dA, (dt * u) * Bv);
    }
    size_t o = (size_t)ch * NREC + (size_t)g * 64 + lane;
    Pbuf[o] = P;
    Ebuf[o] = E;
}

// ---------------------------------------------------------------- k_scan2
// Serial combine over NCH chunks per recurrence; Ebuf becomes Hbuf (h_in) in-place.
__global__ __launch_bounds__(256) void k_scan2(const float* __restrict__ Pbuf,
                                               float* __restrict__ Ebuf) {
    int t = blockIdx.x * 256 + threadIdx.x;   // [0, NREC)
    float h = 0.f;
#pragma unroll
    for (int c = 0; c < NCH; c++) {
        size_t o = (size_t)c * NREC + t;
        float P = Pbuf[o];
        float E = Ebuf[o];
        Ebuf[o] = h;                 // h_in for chunk c
        h = fmaf(P, h, E);
    }
}

// ---------------------------------------------------------------- k_scan3
// Re-run each chunk from h_in; y via LDS 64x65 tile transpose (no shuffles).
__global__ __launch_bounds__(128) void k_scan3(const float* __restrict__ dtt,
                                               const float* __restrict__ xdbl,
                                               const float* __restrict__ xic,
                                               const float* __restrict__ A_log,
                                               const float* __restrict__ Dp,
                                               const float* __restrict__ Hbuf,
                                               float* __restrict__ ys) {
    __shared__ float sm[2][64][65];
    int wid = threadIdx.x >> 6, lane = threadIdx.x & 63;
    int w = blockIdx.x * 2 + wid;          // [0, 32768)
    int d = w & 511;
    int bk = (w >> 9) & 7;
    int ch = w >> 12;
    int k = bk & 3;
    int g = bk * 512 + d;
    const float* dtp = dtt + (size_t)g * Ln;
    const float* xdb = xdbl + (size_t)bk * Ln * 144;
    const float* xcb = xic + (size_t)(bk >> 2) * Ln * DIn + d;
    float* ysp = ys + (size_t)g * Ln;
    float Aln = -__expf(A_log[(size_t)(k * DIn + d) * DSn + lane]);
    float Dv  = Dp[k * DIn + d];
    float h = Hbuf[(size_t)ch * NREC + (size_t)g * 64 + lane];
    float (*tile)[65] = sm[wid];
    for (int t = 0; t < 2; t++) {
        int l0 = ch * CL + t * 64;
#pragma unroll 4
        for (int j = 0; j < 64; j++) {
            int l = l0 + j;
            float dt = dtp[l];
            float u  = xcb[(size_t)permidx(k, l) * DIn];
            float Bv = xdb[l * 144 + 16 + lane];
            float Cv = xdb[l * 144 + 80 + lane];
            float dA = __expf(dt * Aln);
            h = fmaf(h, dA, (dt * u) * Bv);
            tile[j][lane] = fmaf(h, Cv, (lane == 0) ? u * Dv : 0.f);
        }
        // same-wave LDS: compiler inserts lgkmcnt waits; no barrier needed
        float acc = 0.f;
#pragma unroll 8
        for (int s = 0; s < 64; s++) acc += tile[lane][s];
        ysp[l0 + lane] = acc;
    }
}

// ---------------------------------------------------------------- k_comb
__global__ __launch_bounds__(512) void k_comb(const float* __restrict__ ys,
                                              const float* __restrict__ xz,
                                              const float* __restrict__ ln_w,
                                              const float* __restrict__ ln_b,
                                              float* __restrict__ yc) {
    int b = blockIdx.y, l = blockIdx.x, d = threadIdx.x;
    int tpl = ((l & 31) << 5) | (l >> 5);
    const float* yb = ys + (size_t)b * 4 * DIn * Ln;
    float v = yb[(size_t)d * Ln + l]
            + yb[(size_t)(DIn + d) * Ln + tpl]
            + yb[(size_t)(2 * DIn + d) * Ln + (Ln - 1 - l)]
            + yb[(size_t)(3 * DIn + d) * Ln + (Ln - 1 - tpl)];
    float s1 = v, s2 = v * v;
#pragma unroll
    for (int o = 32; o > 0; o >>= 1) { s1 += __shfl_xor(s1, o); s2 += __shfl_xor(s2, o); }
    __shared__ float red[16];
    int wid = threadIdx.x >> 6, lane = threadIdx.x & 63;
    if (lane == 0) { red[wid * 2] = s1; red[wid * 2 + 1] = s2; }
    __syncthreads();
    s1 = 0.f; s2 = 0.f;
#pragma unroll
    for (int w = 0; w < 8; w++) { s1 += red[w * 2]; s2 += red[w * 2 + 1]; }
    float mu  = s1 * (1.f / DIn);
    float var = s2 * (1.f / DIn) - mu * mu;
    float r   = rsqrtf(var + 1e-6f);
    float z   = xz[((size_t)(b << 10) + l) * 1024 + DIn + d];
    yc[((size_t)(b << 10) + l) * DIn + d] = ((v - mu) * r * ln_w[d] + ln_b[d]) * silu_f(z);
}

// ---------------------------------------------------------------- launch
extern "C" void kernel_launch(void* const* d_in, const int* in_sizes, int n_in,
                              void* d_out, int out_size, void* d_ws, size_t ws_size,
                              hipStream_t stream) {
    const float* x      = (const float*)d_in[0];
    const float* c      = (const float*)d_in[1];
    const float* W_ada  = (const float*)d_in[2];
    const float* b_ada  = (const float*)d_in[3];
    const float* W_in   = (const float*)d_in[4];
    const float* b_in   = (const float*)d_in[5];
    const float* conv_w = (const float*)d_in[6];
    const float* conv_b = (const float*)d_in[7];
    const float* W_xp   = (const float*)d_in[8];
    const float* W_dtw  = (const float*)d_in[9];
    const float* dt_b   = (const float*)d_in[10];
    const float* A_log  = (const float*)d_in[11];
    const float* Dp     = (const float*)d_in[12];
    const float* ln_w   = (const float*)d_in[13];
    const float* ln_b   = (const float*)d_in[14];
    const float* W_out  = (const float*)d_in[15];
    const float* b_out  = (const float*)d_in[16];
    const float* W_fc1  = (const float*)d_in[17];
    const float* b_fc1  = (const float*)d_in[18];
    const float* W_fc2  = (const float*)d_in[19];
    const float* b_fc2  = (const float*)d_in[20];
    float* out = (float*)d_out;
    float* ws  = (float*)d_ws;

    // workspace layout (floats)
    float* mod   = ws;                  // 3072
    float* hmod  = mod + 3072;          // 524288
    float* xz    = hmod + 524288;       // 2097152
    float* xic   = xz + 2097152;        // 1048576
    float* xdbl  = xic + 1048576;       // 1179648
    float* dtt   = xdbl + 1179648;      // 4194304
    float* ys    = dtt + 4194304;       // 4194304
    float* ycomb = ys + 4194304;        // 1048576
    float* x1    = ycomb + 1048576;     // 524288
    float* Ebuf  = x1 + 524288;         // 2097152 (NCH*NREC) — doubles as Hbuf
    float* Pbuf  = ys;                  // alias: dead before ys written (scan3)
    float* m0    = hmod;                // alias: hmod dead after W_in GEMM
    float* m1    = xz;                  // alias: xz dead after k_comb

    k_mod<<<dim3(6, Bn), 256, 0, stream>>>(c, W_ada, b_ada, mod);
    k_ln_mod<<<dim3(Ln, Bn), 256, 0, stream>>>(x, mod, 0, 256, hmod);
    gemm64<0><<<dim3(16, 32), 256, 0, stream>>>(hmod, W_in, b_in, xz, 1024, 256,
                                                nullptr, nullptr, 0);
    k_conv<<<dim3(4096), 256, 0, stream>>>(xz, conv_w, conv_b, xic);
    gemm_xdbl<<<dim3(3, 32, Bn * Kn), 256, 0, stream>>>(xic, W_xp, xdbl);
    k_dt<<<dim3(16, 8, Bn * Kn), 256, 0, stream>>>(xdbl, W_dtw, dt_b, dtt);
    k_scan1<<<dim3(8192), 256, 0, stream>>>(dtt, xdbl, xic, A_log, Pbuf, Ebuf);
    k_scan2<<<dim3(1024), 256, 0, stream>>>(Pbuf, Ebuf);
    k_scan3<<<dim3(16384), 128, 0, stream>>>(dtt, xdbl, xic, A_log, Dp, Ebuf, ys);
    k_comb<<<dim3(Ln, Bn), 512, 0, stream>>>(ys, xz, ln_w, ln_b, ycomb);
    gemm64<2><<<dim3(4, 32), 256, 0, stream>>>(ycomb, W_out, b_out, x1, 256, 512,
                                               x, mod, 512);
    k_ln_mod<<<dim3(Ln, Bn), 256, 0, stream>>>(x1, mod, 768, 1024, m0);
    gemm64<1><<<dim3(16, 32), 256, 0, stream>>>(m0, W_fc1, b_fc1, m1, 1024, 256,
                                                nullptr, nullptr, 0);
    gemm64<2><<<dim3(4, 32), 256, 0, stream>>>(m1, W_fc2, b_fc2, out, 256, 1024,
                                               x1, mod, 1280);
}

// Round 3
// 584.556 us; speedup vs baseline: 2.3021x; 2.3021x over previous
//
#include <hip/hip_runtime.h>
#include <math.h>

// Problem constants (from reference)
#define Bn   2
#define Ln   1024
#define DIMn 256
#define DIn  512
#define DSn  64
#define DTRn 16
#define Kn   4
#define HIDn 1024
#define NCH  16         // scan chunks
#define CLn  64         // chunk length (NCH*CLn == Ln)
#define NREC 262144     // b*k*d*s recurrences = 2*4*512*64

__device__ __forceinline__ float silu_f(float x) { return x / (1.f + __expf(-x)); }
__device__ __forceinline__ float softplus_f(float x) { return (x > 20.f) ? x : log1pf(__expf(x)); }
__device__ __forceinline__ float gelu_f(float x) {
    float x3 = x * x * x;
    float t = tanhf(0.7978845608028654f * (x + 0.044715f * x3));
    return 0.5f * x * (1.f + t);
}
// scan-direction index permutation: xs[b,k,l,:] = xic[b, permidx(k,l), :]
__device__ __forceinline__ int permidx(int k, int l) {
    switch (k & 3) {
        case 0:  return l;
        case 1:  return ((l & 31) << 5) | (l >> 5);
        case 2:  return (Ln - 1) - l;
        default: { int j = (Ln - 1) - l; return ((j & 31) << 5) | (j >> 5); }
    }
}

// ---------------------------------------------------------------- k_mod
__global__ __launch_bounds__(256) void k_mod(const float* __restrict__ c,
                                             const float* __restrict__ W,
                                             const float* __restrict__ bias,
                                             float* __restrict__ mod) {
    __shared__ float sc[DIMn];
    int b = blockIdx.y;
    int j = blockIdx.x * 256 + threadIdx.x;
    sc[threadIdx.x] = silu_f(c[b * DIMn + threadIdx.x]);
    __syncthreads();
    float acc = bias[j];
#pragma unroll 4
    for (int r = 0; r < DIMn; r++) acc = fmaf(sc[r], W[r * 1536 + j], acc);
    mod[b * 1536 + j] = acc;
}

// ---------------------------------------------------------------- k_ln_mod
__global__ __launch_bounds__(256) void k_ln_mod(const float* __restrict__ x,
                                                const float* __restrict__ mod,
                                                int sh_ofs, int sc_ofs,
                                                float* __restrict__ out) {
    int b = blockIdx.y, l = blockIdx.x, d = threadIdx.x;
    float v = x[((size_t)(b << 10) + l) * DIMn + d];
    float s1 = v, s2 = v * v;
#pragma unroll
    for (int o = 32; o > 0; o >>= 1) { s1 += __shfl_xor(s1, o); s2 += __shfl_xor(s2, o); }
    __shared__ float red[8];
    int wid = threadIdx.x >> 6, lane = threadIdx.x & 63;
    if (lane == 0) { red[wid * 2] = s1; red[wid * 2 + 1] = s2; }
    __syncthreads();
    s1 = red[0] + red[2] + red[4] + red[6];
    s2 = red[1] + red[3] + red[5] + red[7];
    float mu  = s1 * (1.f / DIMn);
    float var = s2 * (1.f / DIMn) - mu * mu;
    float r   = rsqrtf(var + 1e-6f);
    float sh  = mod[b * 1536 + sh_ofs + d];
    float scv = mod[b * 1536 + sc_ofs + d];
    out[((size_t)(b << 10) + l) * DIMn + d] = (v - mu) * r * (1.f + scv) + sh;
}

// ---------------------------------------------------------------- gemm64
// EPI 0: +bias   EPI 1: gelu(+bias)   EPI 2: resid + mod[b,gofs+n]*(+bias)
template <int EPI>
__global__ __launch_bounds__(256) void gemm64(const float* __restrict__ A,
                                              const float* __restrict__ W,
                                              const float* __restrict__ bias,
                                              float* __restrict__ out,
                                              int N, int Kd,
                                              const float* __restrict__ resid,
                                              const float* __restrict__ mod,
                                              int gofs) {
    __shared__ float As[16][68];
    __shared__ float Bs[16][68];
    int row0 = blockIdx.y << 6, col0 = blockIdx.x << 6;
    int tx = threadIdx.x & 15, ty = threadIdx.x >> 4;
    float acc[4][4] = {};
    for (int k0 = 0; k0 < Kd; k0 += 16) {
#pragma unroll
        for (int i = 0; i < 4; i++) {
            int idx = threadIdx.x + i * 256;
            int m = idx >> 4, kk = idx & 15;
            As[kk][m] = A[(size_t)(row0 + m) * Kd + k0 + kk];
            int n = idx & 63, k2 = idx >> 6;
            int col = col0 + n;
            Bs[k2][n] = (col < N) ? W[(size_t)(k0 + k2) * N + col] : 0.f;
        }
        __syncthreads();
#pragma unroll
        for (int kk = 0; kk < 16; kk++) {
            float a[4], bb[4];
#pragma unroll
            for (int i = 0; i < 4; i++) a[i] = As[kk][ty * 4 + i];
#pragma unroll
            for (int j = 0; j < 4; j++) bb[j] = Bs[kk][tx * 4 + j];
#pragma unroll
            for (int i = 0; i < 4; i++)
#pragma unroll
                for (int j = 0; j < 4; j++) acc[i][j] = fmaf(a[i], bb[j], acc[i][j]);
        }
        __syncthreads();
    }
#pragma unroll
    for (int i = 0; i < 4; i++) {
        int row = row0 + ty * 4 + i;
#pragma unroll
        for (int j = 0; j < 4; j++) {
            int col = col0 + tx * 4 + j;
            if (col < N) {
                float v = acc[i][j] + bias[col];
                if (EPI == 1) v = gelu_f(v);
                if (EPI == 2) v = resid[(size_t)row * N + col] +
                                  mod[(row >> 10) * 1536 + gofs + col] * v;
                out[(size_t)row * N + col] = v;
            }
        }
    }
}

// ---------------------------------------------------------------- gemm_xdbl
__global__ __launch_bounds__(256) void gemm_xdbl(const float* __restrict__ xic,
                                                 const float* __restrict__ Wx,
                                                 float* __restrict__ xdbl) {
    __shared__ float As[16][68];
    __shared__ float Bs[16][68];
    int bk = blockIdx.z;              // b*4+k
    int b = bk >> 2, k = bk & 3;
    int row0 = blockIdx.y << 6, col0 = blockIdx.x << 6;
    const float* Ab = xic + (size_t)b * Ln * DIn;
    const float* Wb = Wx + (size_t)k * DIn * 144;
    float* ob = xdbl + (size_t)bk * Ln * 144;
    int tx = threadIdx.x & 15, ty = threadIdx.x >> 4;
    float acc[4][4] = {};
    for (int k0 = 0; k0 < DIn; k0 += 16) {
#pragma unroll
        for (int i = 0; i < 4; i++) {
            int idx = threadIdx.x + i * 256;
            int m = idx >> 4, kk = idx & 15;
            As[kk][m] = Ab[(size_t)permidx(k, row0 + m) * DIn + k0 + kk];
            int n = idx & 63, k2 = idx >> 6;
            int col = col0 + n;
            Bs[k2][n] = (col < 144) ? Wb[(size_t)(k0 + k2) * 144 + col] : 0.f;
        }
        __syncthreads();
#pragma unroll
        for (int kk = 0; kk < 16; kk++) {
            float a[4], bb[4];
#pragma unroll
            for (int i = 0; i < 4; i++) a[i] = As[kk][ty * 4 + i];
#pragma unroll
            for (int j = 0; j < 4; j++) bb[j] = Bs[kk][tx * 4 + j];
#pragma unroll
            for (int i = 0; i < 4; i++)
#pragma unroll
                for (int j = 0; j < 4; j++) acc[i][j] = fmaf(a[i], bb[j], acc[i][j]);
        }
        __syncthreads();
    }
#pragma unroll
    for (int i = 0; i < 4; i++) {
        int row = row0 + ty * 4 + i;
#pragma unroll
        for (int j = 0; j < 4; j++) {
            int col = col0 + tx * 4 + j;
            if (col < 144) ob[(size_t)row * 144 + col] = acc[i][j];
        }
    }
}

// ---------------------------------------------------------------- k_conv
__global__ __launch_bounds__(256) void k_conv(const float* __restrict__ xz,
                                              const float* __restrict__ cw,
                                              const float* __restrict__ cb,
                                              float* __restrict__ xic) {
    int idx = blockIdx.x * 256 + threadIdx.x;   // b*L*512 + l*512 + d
    int d = idx & 511;
    int l = (idx >> 9) & 1023;
    int b = idx >> 19;
    int hh = l >> 5, ww = l & 31;
    float acc = cb[d];
#pragma unroll
    for (int ky = 0; ky < 3; ky++) {
        int y = hh + ky - 1;
        if ((unsigned)y >= 32u) continue;
#pragma unroll
        for (int kx = 0; kx < 3; kx++) {
            int xw = ww + kx - 1;
            if ((unsigned)xw >= 32u) continue;
            acc = fmaf(cw[(ky * 3 + kx) * DIn + d],
                       xz[((size_t)(b << 10) + (y << 5) + xw) * 1024 + d], acc);
        }
    }
    xic[idx] = silu_f(acc);
}

// ---------------------------------------------------------------- k_dt
// dtl[bk,l,d] = softplus(xdbl[bk,l,0:16] @ W_dt[k] + dt_bias[k,d]) — natural layout
__global__ __launch_bounds__(256) void k_dt(const float* __restrict__ xdbl,
                                            const float* __restrict__ W_dt,
                                            const float* __restrict__ dt_bias,
                                            float* __restrict__ dtl) {
    __shared__ float Ar[64][16];
    __shared__ float Wd[16][64];
    int bk = blockIdx.z, k = bk & 3;
    int l0 = blockIdx.x << 6, d0 = blockIdx.y << 6;
    const float* xb = xdbl + (size_t)bk * Ln * 144;
    int tid = threadIdx.x;
    {   // stage dt_r rows (64 x 16) and W_dt tile (16 x 64)
        int row = tid >> 2, c4 = tid & 3;
        *(float4*)&Ar[row][c4 * 4] = *(const float4*)&xb[(size_t)(l0 + row) * 144 + c4 * 4];
        int r = tid >> 4, c4b = tid & 15;
        *(float4*)&Wd[r][c4b * 4] = *(const float4*)&W_dt[(size_t)(k * 16 + r) * DIn + d0 + c4b * 4];
    }
    __syncthreads();
    int dl = tid & 63, lq = tid >> 6;
    float bias = dt_bias[k * DIn + d0 + dl];
#pragma unroll
    for (int i = 0; i < 16; i++) {
        int lr = lq * 16 + i;
        float acc = bias;
#pragma unroll
        for (int r = 0; r < 16; r++) acc = fmaf(Ar[lr][r], Wd[r][dl], acc);
        dtl[((size_t)(bk << 10) + l0 + lr) * DIn + d0 + dl] = softplus_f(acc);
    }
}

// ---------------------------------------------------------------- k_scanA
// lanes = d; each thread owns 32 states in regs. Per (bk, chunk, dgrp, shalf) wave:
// E endpoint (h from 0) per state + P = exp(Aln * sum(dt)).
__global__ __launch_bounds__(256) void k_scanA(const float* __restrict__ dtl,
                                               const float* __restrict__ xdbl,
                                               const float* __restrict__ xic,
                                               const float* __restrict__ A_log,
                                               float* __restrict__ Pbuf,
                                               float* __restrict__ Ebuf) {
    __shared__ float Bs[64][64];
    int bx = blockIdx.x;
    int bk = bx & 7, ch = (bx >> 3) & 15, dpair = bx >> 7;
    int k = bk & 3, b = bk >> 2;
    int tid = threadIdx.x;
    int wid = tid >> 6, lane = tid & 63;
    int sh = wid & 1, dgrp = dpair * 2 + (wid >> 1);
    int d = dgrp * 64 + lane;
    int l0 = ch * CLn;
    const float* xdb = xdbl + (size_t)bk * Ln * 144;
#pragma unroll
    for (int p = 0; p < 4; p++) {
        int f4 = p * 256 + tid;
        int row = f4 >> 4, c4 = f4 & 15;
        *(float4*)&Bs[row][c4 * 4] =
            *(const float4*)&xdb[(size_t)(l0 + row) * 144 + 16 + c4 * 4];
    }
    __syncthreads();
    float Aln[32], h[32];
#pragma unroll
    for (int s = 0; s < 32; s++) {
        Aln[s] = -__expf(A_log[(size_t)(k * DIn + d) * DSn + sh * 32 + s]);
        h[s] = 0.f;
    }
    const float* dtp = dtl + ((size_t)(bk << 10)) * DIn + d;
    const float* xcb = xic + ((size_t)(b << 10)) * DIn + d;
    float dtsum = 0.f;
#pragma unroll 2
    for (int j = 0; j < CLn; j++) {
        int l = l0 + j;
        float dt = dtp[(size_t)l * DIn];
        float u  = xcb[(size_t)permidx(k, l) * DIn];
        float du = dt * u;
        dtsum += dt;
#pragma unroll
        for (int s4 = 0; s4 < 8; s4++) {
            float4 bv = *(const float4*)&Bs[j][sh * 32 + s4 * 4];
            h[s4*4+0] = fmaf(h[s4*4+0], __expf(dt * Aln[s4*4+0]), du * bv.x);
            h[s4*4+1] = fmaf(h[s4*4+1], __expf(dt * Aln[s4*4+1]), du * bv.y);
            h[s4*4+2] = fmaf(h[s4*4+2], __expf(dt * Aln[s4*4+2]), du * bv.z);
            h[s4*4+3] = fmaf(h[s4*4+3], __expf(dt * Aln[s4*4+3]), du * bv.w);
        }
    }
    size_t o0 = (size_t)(((ch * 8 + bk) * 2 + sh) * 32) * DIn + d;
#pragma unroll
    for (int s = 0; s < 32; s++) {
        Pbuf[o0 + (size_t)s * DIn] = __expf(dtsum * Aln[s]);
        Ebuf[o0 + (size_t)s * DIn] = h[s];
    }
}

// ---------------------------------------------------------------- k_scan2
// Serial combine over NCH chunks per recurrence; Ebuf becomes Hbuf (h_in) in-place.
__global__ __launch_bounds__(256) void k_scan2(const float* __restrict__ Pbuf,
                                               float* __restrict__ Ebuf) {
    int t = blockIdx.x * 256 + threadIdx.x;   // [0, NREC)
    float h = 0.f;
#pragma unroll
    for (int c = 0; c < NCH; c++) {
        size_t o = (size_t)c * NREC + t;
        float P = Pbuf[o];
        float E = Ebuf[o];
        Ebuf[o] = h;                 // h_in for chunk c
        h = fmaf(P, h, E);
    }
}

// ---------------------------------------------------------------- k_scanB
// Re-run each chunk from h_in; per-thread y accumulation (no cross-lane reduce).
// yt0/yt1 hold the two s-half partials, layout [bk][l][d] (coalesced).
__global__ __launch_bounds__(256) void k_scanB(const float* __restrict__ dtl,
                                               const float* __restrict__ xdbl,
                                               const float* __restrict__ xic,
                                               const float* __restrict__ A_log,
                                               const float* __restrict__ Dp,
                                               const float* __restrict__ Hbuf,
                                               float* __restrict__ yt0,
                                               float* __restrict__ yt1) {
    __shared__ float Bs[64][64];
    __shared__ float Cs[64][64];
    int bx = blockIdx.x;
    int bk = bx & 7, ch = (bx >> 3) & 15, dpair = bx >> 7;
    int k = bk & 3, b = bk >> 2;
    int tid = threadIdx.x;
    int wid = tid >> 6, lane = tid & 63;
    int sh = wid & 1, dgrp = dpair * 2 + (wid >> 1);
    int d = dgrp * 64 + lane;
    int l0 = ch * CLn;
    const float* xdb = xdbl + (size_t)bk * Ln * 144;
#pragma unroll
    for (int p = 0; p < 4; p++) {
        int f4 = p * 256 + tid;
        int row = f4 >> 4, c4 = f4 & 15;
        *(float4*)&Bs[row][c4 * 4] =
            *(const float4*)&xdb[(size_t)(l0 + row) * 144 + 16 + c4 * 4];
        *(float4*)&Cs[row][c4 * 4] =
            *(const float4*)&xdb[(size_t)(l0 + row) * 144 + 80 + c4 * 4];
    }
    __syncthreads();
    float Aln[32], h[32];
    size_t o0 = (size_t)(((ch * 8 + bk) * 2 + sh) * 32) * DIn + d;
#pragma unroll
    for (int s = 0; s < 32; s++) {
        Aln[s] = -__expf(A_log[(size_t)(k * DIn + d) * DSn + sh * 32 + s]);
        h[s] = Hbuf[o0 + (size_t)s * DIn];
    }
    const float* dtp = dtl + ((size_t)(bk << 10)) * DIn + d;
    const float* xcb = xic + ((size_t)(b << 10)) * DIn + d;
    float Dv = Dp[k * DIn + d];
    float* yts = (sh == 0) ? yt0 : yt1;
#pragma unroll 2
    for (int j = 0; j < CLn; j++) {
        int l = l0 + j;
        float dt = dtp[(size_t)l * DIn];
        float u  = xcb[(size_t)permidx(k, l) * DIn];
        float du = dt * u;
        float yp = (sh == 0) ? u * Dv : 0.f;
#pragma unroll
        for (int s4 = 0; s4 < 8; s4++) {
            float4 bv = *(const float4*)&Bs[j][sh * 32 + s4 * 4];
            float4 cv = *(const float4*)&Cs[j][sh * 32 + s4 * 4];
            h[s4*4+0] = fmaf(h[s4*4+0], __expf(dt * Aln[s4*4+0]), du * bv.x);
            yp = fmaf(h[s4*4+0], cv.x, yp);
            h[s4*4+1] = fmaf(h[s4*4+1], __expf(dt * Aln[s4*4+1]), du * bv.y);
            yp = fmaf(h[s4*4+1], cv.y, yp);
            h[s4*4+2] = fmaf(h[s4*4+2], __expf(dt * Aln[s4*4+2]), du * bv.z);
            yp = fmaf(h[s4*4+2], cv.z, yp);
            h[s4*4+3] = fmaf(h[s4*4+3], __expf(dt * Aln[s4*4+3]), du * bv.w);
            yp = fmaf(h[s4*4+3], cv.w, yp);
        }
        yts[((size_t)(bk << 10) + l) * DIn + d] = yp;
    }
}

// ---------------------------------------------------------------- k_comb
// ycomb[b,l,:] = (LN_512(sum of 4 permuted directions)*ln_w + ln_b) * silu(z)
__global__ __launch_bounds__(512) void k_comb(const float* __restrict__ yt0,
                                              const float* __restrict__ yt1,
                                              const float* __restrict__ xz,
                                              const float* __restrict__ ln_w,
                                              const float* __restrict__ ln_b,
                                              float* __restrict__ yc) {
    int b = blockIdx.y, l = blockIdx.x, d = threadIdx.x;
    int tpl = ((l & 31) << 5) | (l >> 5);
    int b4 = b << 2;
    size_t i0 = ((size_t)((b4 + 0) << 10) + l) * DIn + d;
    size_t i1 = ((size_t)((b4 + 1) << 10) + tpl) * DIn + d;
    size_t i2 = ((size_t)((b4 + 2) << 10) + (Ln - 1 - l)) * DIn + d;
    size_t i3 = ((size_t)((b4 + 3) << 10) + (Ln - 1 - tpl)) * DIn + d;
    float v = yt0[i0] + yt1[i0] + yt0[i1] + yt1[i1]
            + yt0[i2] + yt1[i2] + yt0[i3] + yt1[i3];
    float s1 = v, s2 = v * v;
#pragma unroll
    for (int o = 32; o > 0; o >>= 1) { s1 += __shfl_xor(s1, o); s2 += __shfl_xor(s2, o); }
    __shared__ float red[16];
    int wid = threadIdx.x >> 6, lane = threadIdx.x & 63;
    if (lane == 0) { red[wid * 2] = s1; red[wid * 2 + 1] = s2; }
    __syncthreads();
    s1 = 0.f; s2 = 0.f;
#pragma unroll
    for (int w = 0; w < 8; w++) { s1 += red[w * 2]; s2 += red[w * 2 + 1]; }
    float mu  = s1 * (1.f / DIn);
    float var = s2 * (1.f / DIn) - mu * mu;
    float r   = rsqrtf(var + 1e-6f);
    float z   = xz[((size_t)(b << 10) + l) * 1024 + DIn + d];
    yc[((size_t)(b << 10) + l) * DIn + d] = ((v - mu) * r * ln_w[d] + ln_b[d]) * silu_f(z);
}

// ---------------------------------------------------------------- launch
extern "C" void kernel_launch(void* const* d_in, const int* in_sizes, int n_in,
                              void* d_out, int out_size, void* d_ws, size_t ws_size,
                              hipStream_t stream) {
    const float* x      = (const float*)d_in[0];
    const float* c      = (const float*)d_in[1];
    const float* W_ada  = (const float*)d_in[2];
    const float* b_ada  = (const float*)d_in[3];
    const float* W_in   = (const float*)d_in[4];
    const float* b_in   = (const float*)d_in[5];
    const float* conv_w = (const float*)d_in[6];
    const float* conv_b = (const float*)d_in[7];
    const float* W_xp   = (const float*)d_in[8];
    const float* W_dtw  = (const float*)d_in[9];
    const float* dt_b   = (const float*)d_in[10];
    const float* A_log  = (const float*)d_in[11];
    const float* Dp     = (const float*)d_in[12];
    const float* ln_w   = (const float*)d_in[13];
    const float* ln_b   = (const float*)d_in[14];
    const float* W_out  = (const float*)d_in[15];
    const float* b_out  = (const float*)d_in[16];
    const float* W_fc1  = (const float*)d_in[17];
    const float* b_fc1  = (const float*)d_in[18];
    const float* W_fc2  = (const float*)d_in[19];
    const float* b_fc2  = (const float*)d_in[20];
    float* out = (float*)d_out;
    float* ws  = (float*)d_ws;

    // workspace layout (floats)
    float* mod   = ws;                  // 3072
    float* hmod  = mod + 3072;          // 524288
    float* xz    = hmod + 524288;       // 2097152
    float* xic   = xz + 2097152;        // 1048576
    float* xdbl  = xic + 1048576;       // 1179648
    float* dtl   = xdbl + 1179648;      // 4194304
    float* Ebuf  = dtl + 4194304;       // 4194304 (NCH*NREC) — doubles as Hbuf
    float* yt0   = Ebuf + 4194304;      // 4194304
    float* yt1   = yt0 + 4194304;       // 4194304
    float* ycomb = yt1 + 4194304;       // 1048576
    float* x1    = ycomb + 1048576;     // 524288
    float* Pbuf  = yt1;                 // alias: P dead before scanB writes yt1
    float* m0    = hmod;                // alias: hmod dead after W_in GEMM
    float* m1    = xz;                  // alias: xz dead after k_comb

    k_mod<<<dim3(6, Bn), 256, 0, stream>>>(c, W_ada, b_ada, mod);
    k_ln_mod<<<dim3(Ln, Bn), 256, 0, stream>>>(x, mod, 0, 256, hmod);
    gemm64<0><<<dim3(16, 32), 256, 0, stream>>>(hmod, W_in, b_in, xz, 1024, 256,
                                                nullptr, nullptr, 0);
    k_conv<<<dim3(4096), 256, 0, stream>>>(xz, conv_w, conv_b, xic);
    gemm_xdbl<<<dim3(3, 32, Bn * Kn), 256, 0, stream>>>(xic, W_xp, xdbl);
    k_dt<<<dim3(16, 8, Bn * Kn), 256, 0, stream>>>(xdbl, W_dtw, dt_b, dtl);
    k_scanA<<<dim3(512), 256, 0, stream>>>(dtl, xdbl, xic, A_log, Pbuf, Ebuf);
    k_scan2<<<dim3(1024), 256, 0, stream>>>(Pbuf, Ebuf);
    k_scanB<<<dim3(512), 256, 0, stream>>>(dtl, xdbl, xic, A_log, Dp, Ebuf, yt0, yt1);
    k_comb<<<dim3(Ln, Bn), 512, 0, stream>>>(yt0, yt1, xz, ln_w, ln_b, ycomb);
    gemm64<2><<<dim3(4, 32), 256, 0, stream>>>(ycomb, W_out, b_out, x1, 256, 512,
                                               x, mod, 512);
    k_ln_mod<<<dim3(Ln, Bn), 256, 0, stream>>>(x1, mod, 768, 1024, m0);
    gemm64<1><<<dim3(16, 32), 256, 0, stream>>>(m0, W_fc1, b_fc1, m1, 1024, 256,
                                                nullptr, nullptr, 0);
    gemm64<2><<<dim3(4, 32), 256, 0, stream>>>(m1, W_fc2, b_fc2, out, 256, 1024,
                                               x1, mod, 1280);
}

// Round 4
// 348.239 us; speedup vs baseline: 3.8644x; 1.6786x over previous
//
#include <hip/hip_runtime.h>
#include <hip/hip_bf16.h>
#include <math.h>

// Problem constants (from reference)
#define Bn   2
#define Ln   1024
#define DIMn 256
#define DIn  512
#define DSn  64
#define DTRn 16
#define Kn   4
#define HIDn 1024
#define NCH  16         // scan chunks
#define CLn  64         // chunk length (NCH*CLn == Ln)
#define NREC 262144     // b*k*d*s recurrences = 2*4*512*64

typedef __attribute__((ext_vector_type(8))) short short8;   // 8 bf16 (4 VGPRs)
typedef __attribute__((ext_vector_type(4))) float floatx4;  // MFMA acc
typedef __hip_bfloat16 bf16;

__device__ __forceinline__ float silu_f(float x) { return x / (1.f + __expf(-x)); }
__device__ __forceinline__ float softplus_f(float x) { return (x > 20.f) ? x : log1pf(__expf(x)); }
__device__ __forceinline__ float gelu_f(float x) {
    float x3 = x * x * x;
    float t = tanhf(0.7978845608028654f * (x + 0.044715f * x3));
    return 0.5f * x * (1.f + t);
}
// scan-direction index permutation: xs[b,k,l,:] = xic[b, permidx(k,l), :]
__device__ __forceinline__ int permidx(int k, int l) {
    switch (k & 3) {
        case 0:  return l;
        case 1:  return ((l & 31) << 5) | (l >> 5);
        case 2:  return (Ln - 1) - l;
        default: { int j = (Ln - 1) - l; return ((j & 31) << 5) | (j >> 5); }
    }
}

// ---------------------------------------------------------------- k_mod
__global__ __launch_bounds__(256) void k_mod(const float* __restrict__ c,
                                             const float* __restrict__ W,
                                             const float* __restrict__ bias,
                                             float* __restrict__ mod) {
    __shared__ float sc[DIMn];
    int b = blockIdx.y;
    int j = blockIdx.x * 256 + threadIdx.x;
    sc[threadIdx.x] = silu_f(c[b * DIMn + threadIdx.x]);
    __syncthreads();
    float acc = bias[j];
#pragma unroll 4
    for (int r = 0; r < DIMn; r++) acc = fmaf(sc[r], W[r * 1536 + j], acc);
    mod[b * 1536 + j] = acc;
}

// ---------------------------------------------------------------- k_wt
// Wt[n][k] = bf16(W[k][n]); rows n in [N, Npad) zero-filled. z batches matrices.
__global__ __launch_bounds__(256) void k_wt(const float* __restrict__ W,
                                            bf16* __restrict__ Wt,
                                            int K, int N, int Npad) {
    __shared__ float sm[32][33];
    int n0 = blockIdx.x * 32, k0 = blockIdx.y * 32;
    int z = blockIdx.z;
    W  += (size_t)z * K * N;
    Wt += (size_t)z * Npad * K;
    int tc = threadIdx.x & 31, tr = threadIdx.x >> 5;   // 8 rows x 32 cols
#pragma unroll
    for (int i = 0; i < 4; i++) {
        int n = n0 + tc;
        sm[tr + i * 8][tc] = (n < N) ? W[(size_t)(k0 + tr + i * 8) * N + n] : 0.f;
    }
    __syncthreads();
#pragma unroll
    for (int i = 0; i < 4; i++) {
        int n = n0 + tr + i * 8;
        Wt[(size_t)n * K + k0 + tc] = __float2bfloat16(sm[tc][tr + i * 8]);
    }
}

// ---------------------------------------------------------------- k_ln_mod
// out[b,l,:] = bf16( LN(x) * (1+scale) + shift )
__global__ __launch_bounds__(256) void k_ln_mod(const float* __restrict__ x,
                                                const float* __restrict__ mod,
                                                int sh_ofs, int sc_ofs,
                                                bf16* __restrict__ out) {
    int b = blockIdx.y, l = blockIdx.x, d = threadIdx.x;
    float v = x[((size_t)(b << 10) + l) * DIMn + d];
    float s1 = v, s2 = v * v;
#pragma unroll
    for (int o = 32; o > 0; o >>= 1) { s1 += __shfl_xor(s1, o); s2 += __shfl_xor(s2, o); }
    __shared__ float red[8];
    int wid = threadIdx.x >> 6, lane = threadIdx.x & 63;
    if (lane == 0) { red[wid * 2] = s1; red[wid * 2 + 1] = s2; }
    __syncthreads();
    s1 = red[0] + red[2] + red[4] + red[6];
    s2 = red[1] + red[3] + red[5] + red[7];
    float mu  = s1 * (1.f / DIMn);
    float var = s2 * (1.f / DIMn) - mu * mu;
    float r   = rsqrtf(var + 1e-6f);
    float sh  = mod[b * 1536 + sh_ofs + d];
    float scv = mod[b * 1536 + sc_ofs + d];
    out[((size_t)(b << 10) + l) * DIMn + d] =
        __float2bfloat16((v - mu) * r * (1.f + scv) + sh);
}

// ---------------------------------------------------------------- gemm_bf
// C[M,N] = A[M,K](bf16) @ Wt[N,K](bf16)^T, fp32 acc. 64x64 tile, 4 waves,
// each wave 32x32 via 2x2 16x16x32 MFMA frags.
// EPI -1: raw partial to outf[s][M][N]   EPI 0: +bias -> fp32
// EPI 1: gelu(+bias) -> bf16 outh
template <int EPI>
__global__ __launch_bounds__(256) void gemm_bf(const bf16* __restrict__ A,
                                               const bf16* __restrict__ Wt,
                                               const float* __restrict__ bias,
                                               float* __restrict__ outf,
                                               bf16* __restrict__ outh,
                                               int N, int K, int kpart) {
    __shared__ __align__(16) bf16 Asm[64][40];
    __shared__ __align__(16) bf16 Bsm[64][40];
    int row0 = blockIdx.y << 6, col0 = blockIdx.x << 6;
    int s = blockIdx.z;
    int k0 = s * kpart;
    int tid = threadIdx.x;
    int wv = tid >> 6, lane = tid & 63;
    int wm = (wv >> 1) * 32, wn = (wv & 1) * 32;
    int q = lane >> 4, r = lane & 15;
    int srow = tid >> 2, skb = (tid & 3) * 8;
    floatx4 acc[2][2] = {};
    const short* Ag = (const short*)A;
    const short* Bg = (const short*)Wt;
    for (int kt = 0; kt < kpart; kt += 32) {
        *(uint4*)&Asm[srow][skb] =
            *(const uint4*)&Ag[(size_t)(row0 + srow) * K + k0 + kt + skb];
        *(uint4*)&Bsm[srow][skb] =
            *(const uint4*)&Bg[(size_t)(col0 + srow) * K + k0 + kt + skb];
        __syncthreads();
        short8 a0 = *(const short8*)&Asm[wm + r][q * 8];
        short8 a1 = *(const short8*)&Asm[wm + 16 + r][q * 8];
        short8 b0 = *(const short8*)&Bsm[wn + r][q * 8];
        short8 b1 = *(const short8*)&Bsm[wn + 16 + r][q * 8];
        acc[0][0] = __builtin_amdgcn_mfma_f32_16x16x32_bf16(a0, b0, acc[0][0], 0, 0, 0);
        acc[0][1] = __builtin_amdgcn_mfma_f32_16x16x32_bf16(a0, b1, acc[0][1], 0, 0, 0);
        acc[1][0] = __builtin_amdgcn_mfma_f32_16x16x32_bf16(a1, b0, acc[1][0], 0, 0, 0);
        acc[1][1] = __builtin_amdgcn_mfma_f32_16x16x32_bf16(a1, b1, acc[1][1], 0, 0, 0);
        __syncthreads();
    }
    int M = gridDim.y << 6;
#pragma unroll
    for (int i = 0; i < 2; i++)
#pragma unroll
        for (int j = 0; j < 2; j++) {
            int col = col0 + wn + j * 16 + r;
#pragma unroll
            for (int t = 0; t < 4; t++) {
                int row = row0 + wm + i * 16 + q * 4 + t;
                float v = acc[i][j][t];
                if (EPI == -1) {
                    outf[((size_t)s * M + row) * N + col] = v;
                } else if (EPI == 0) {
                    outf[(size_t)row * N + col] = v + bias[col];
                } else {
                    outh[(size_t)row * N + col] = __float2bfloat16(gelu_f(v + bias[col]));
                }
            }
        }
}

// ---------------------------------------------------------------- gemm_xdbl_bf
// xdbl[bk,l,0:144] = xich[b, permidx(k,l), :] @ Wtx[k]^T  (K=512, N=144 pad 192)
__global__ __launch_bounds__(256) void gemm_xdbl_bf(const bf16* __restrict__ xich,
                                                    const bf16* __restrict__ Wtx,
                                                    float* __restrict__ xdbl) {
    __shared__ __align__(16) bf16 Asm[64][40];
    __shared__ __align__(16) bf16 Bsm[64][40];
    int bk = blockIdx.z, b = bk >> 2, k = bk & 3;
    int row0 = blockIdx.y << 6, col0 = blockIdx.x << 6;
    const short* Ag = (const short*)xich + (size_t)b * Ln * DIn;
    const short* Bg = (const short*)Wtx + (size_t)k * 192 * DIn;
    float* ob = xdbl + (size_t)bk * Ln * 144;
    int tid = threadIdx.x;
    int wv = tid >> 6, lane = tid & 63;
    int wm = (wv >> 1) * 32, wn = (wv & 1) * 32;
    int q = lane >> 4, r = lane & 15;
    int srow = tid >> 2, skb = (tid & 3) * 8;
    int arow = permidx(k, row0 + srow);
    floatx4 acc[2][2] = {};
    for (int kt = 0; kt < DIn; kt += 32) {
        *(uint4*)&Asm[srow][skb] = *(const uint4*)&Ag[(size_t)arow * DIn + kt + skb];
        *(uint4*)&Bsm[srow][skb] = *(const uint4*)&Bg[(size_t)(col0 + srow) * DIn + kt + skb];
        __syncthreads();
        short8 a0 = *(const short8*)&Asm[wm + r][q * 8];
        short8 a1 = *(const short8*)&Asm[wm + 16 + r][q * 8];
        short8 b0 = *(const short8*)&Bsm[wn + r][q * 8];
        short8 b1 = *(const short8*)&Bsm[wn + 16 + r][q * 8];
        acc[0][0] = __builtin_amdgcn_mfma_f32_16x16x32_bf16(a0, b0, acc[0][0], 0, 0, 0);
        acc[0][1] = __builtin_amdgcn_mfma_f32_16x16x32_bf16(a0, b1, acc[0][1], 0, 0, 0);
        acc[1][0] = __builtin_amdgcn_mfma_f32_16x16x32_bf16(a1, b0, acc[1][0], 0, 0, 0);
        acc[1][1] = __builtin_amdgcn_mfma_f32_16x16x32_bf16(a1, b1, acc[1][1], 0, 0, 0);
        __syncthreads();
    }
#pragma unroll
    for (int i = 0; i < 2; i++)
#pragma unroll
        for (int j = 0; j < 2; j++) {
            int col = col0 + wn + j * 16 + r;
            if (col < 144) {
#pragma unroll
                for (int t = 0; t < 4; t++) {
                    int row = row0 + wm + i * 16 + q * 4 + t;
                    ob[(size_t)row * 144 + col] = acc[i][j][t];
                }
            }
        }
}

// ---------------------------------------------------------------- k_redep
// out = resid + mod_gate * (sum_s pred[s] + bias)   (N=256 gemms' epilogue)
__global__ __launch_bounds__(256) void k_redep(const float* __restrict__ pred,
                                               int S,
                                               const float* __restrict__ bias,
                                               const float* __restrict__ resid,
                                               const float* __restrict__ mod,
                                               int gofs,
                                               float* __restrict__ out) {
    int t = blockIdx.x * 256 + threadIdx.x;     // [0, 2048*256)
    int col = t & 255, row = t >> 8;
    float v = 0.f;
    for (int s = 0; s < S; s++) v += pred[(size_t)s * (2048 * 256) + t];
    out[t] = resid[t] + mod[(row >> 10) * 1536 + gofs + col] * (v + bias[col]);
}

// ---------------------------------------------------------------- k_conv
// depthwise 3x3 SAME + bias + silu; writes fp32 xic (scan) and bf16 xich (gemm)
__global__ __launch_bounds__(256) void k_conv(const float* __restrict__ xz,
                                              const float* __restrict__ cw,
                                              const float* __restrict__ cb,
                                              float* __restrict__ xic,
                                              bf16* __restrict__ xich) {
    int idx = blockIdx.x * 256 + threadIdx.x;   // b*L*512 + l*512 + d
    int d = idx & 511;
    int l = (idx >> 9) & 1023;
    int b = idx >> 19;
    int hh = l >> 5, ww = l & 31;
    float acc = cb[d];
#pragma unroll
    for (int ky = 0; ky < 3; ky++) {
        int y = hh + ky - 1;
        if ((unsigned)y >= 32u) continue;
#pragma unroll
        for (int kx = 0; kx < 3; kx++) {
            int xw = ww + kx - 1;
            if ((unsigned)xw >= 32u) continue;
            acc = fmaf(cw[(ky * 3 + kx) * DIn + d],
                       xz[((size_t)(b << 10) + (y << 5) + xw) * 1024 + d], acc);
        }
    }
    float v = silu_f(acc);
    xic[idx] = v;
    xich[idx] = __float2bfloat16(v);
}

// ---------------------------------------------------------------- k_dt
// dtl[bk,l,d] = softplus(xdbl[bk,l,0:16] @ W_dt[k] + dt_bias[k,d]) — natural layout
__global__ __launch_bounds__(256) void k_dt(const float* __restrict__ xdbl,
                                            const float* __restrict__ W_dt,
                                            const float* __restrict__ dt_bias,
                                            float* __restrict__ dtl) {
    __shared__ float Ar[64][16];
    __shared__ float Wd[16][64];
    int bk = blockIdx.z, k = bk & 3;
    int l0 = blockIdx.x << 6, d0 = blockIdx.y << 6;
    const float* xb = xdbl + (size_t)bk * Ln * 144;
    int tid = threadIdx.x;
    {
        int row = tid >> 2, c4 = tid & 3;
        *(float4*)&Ar[row][c4 * 4] = *(const float4*)&xb[(size_t)(l0 + row) * 144 + c4 * 4];
        int r = tid >> 4, c4b = tid & 15;
        *(float4*)&Wd[r][c4b * 4] = *(const float4*)&W_dt[(size_t)(k * 16 + r) * DIn + d0 + c4b * 4];
    }
    __syncthreads();
    int dl = tid & 63, lq = tid >> 6;
    float bias = dt_bias[k * DIn + d0 + dl];
#pragma unroll
    for (int i = 0; i < 16; i++) {
        int lr = lq * 16 + i;
        float acc = bias;
#pragma unroll
        for (int r = 0; r < 16; r++) acc = fmaf(Ar[lr][r], Wd[r][dl], acc);
        dtl[((size_t)(bk << 10) + l0 + lr) * DIn + d0 + dl] = softplus_f(acc);
    }
}

// ---------------------------------------------------------------- k_scanA
__global__ __launch_bounds__(256) void k_scanA(const float* __restrict__ dtl,
                                               const float* __restrict__ xdbl,
                                               const float* __restrict__ xic,
                                               const float* __restrict__ A_log,
                                               float* __restrict__ Pbuf,
                                               float* __restrict__ Ebuf) {
    __shared__ float Bs[64][64];
    int bx = blockIdx.x;
    int bk = bx & 7, ch = (bx >> 3) & 15, dpair = bx >> 7;
    int k = bk & 3, b = bk >> 2;
    int tid = threadIdx.x;
    int wid = tid >> 6, lane = tid & 63;
    int sh = wid & 1, dgrp = dpair * 2 + (wid >> 1);
    int d = dgrp * 64 + lane;
    int l0 = ch * CLn;
    const float* xdb = xdbl + (size_t)bk * Ln * 144;
#pragma unroll
    for (int p = 0; p < 4; p++) {
        int f4 = p * 256 + tid;
        int row = f4 >> 4, c4 = f4 & 15;
        *(float4*)&Bs[row][c4 * 4] =
            *(const float4*)&xdb[(size_t)(l0 + row) * 144 + 16 + c4 * 4];
    }
    __syncthreads();
    float Aln[32], h[32];
#pragma unroll
    for (int s = 0; s < 32; s++) {
        Aln[s] = -__expf(A_log[(size_t)(k * DIn + d) * DSn + sh * 32 + s]);
        h[s] = 0.f;
    }
    const float* dtp = dtl + ((size_t)(bk << 10)) * DIn + d;
    const float* xcb = xic + ((size_t)(b << 10)) * DIn + d;
    float dtsum = 0.f;
#pragma unroll 2
    for (int j = 0; j < CLn; j++) {
        int l = l0 + j;
        float dt = dtp[(size_t)l * DIn];
        float u  = xcb[(size_t)permidx(k, l) * DIn];
        float du = dt * u;
        dtsum += dt;
#pragma unroll
        for (int s4 = 0; s4 < 8; s4++) {
            float4 bv = *(const float4*)&Bs[j][sh * 32 + s4 * 4];
            h[s4*4+0] = fmaf(h[s4*4+0], __expf(dt * Aln[s4*4+0]), du * bv.x);
            h[s4*4+1] = fmaf(h[s4*4+1], __expf(dt * Aln[s4*4+1]), du * bv.y);
            h[s4*4+2] = fmaf(h[s4*4+2], __expf(dt * Aln[s4*4+2]), du * bv.z);
            h[s4*4+3] = fmaf(h[s4*4+3], __expf(dt * Aln[s4*4+3]), du * bv.w);
        }
    }
    size_t o0 = (size_t)(((ch * 8 + bk) * 2 + sh) * 32) * DIn + d;
#pragma unroll
    for (int s = 0; s < 32; s++) {
        Pbuf[o0 + (size_t)s * DIn] = __expf(dtsum * Aln[s]);
        Ebuf[o0 + (size_t)s * DIn] = h[s];
    }
}

// ---------------------------------------------------------------- k_scan2
__global__ __launch_bounds__(256) void k_scan2(const float* __restrict__ Pbuf,
                                               float* __restrict__ Ebuf) {
    int t = blockIdx.x * 256 + threadIdx.x;   // [0, NREC)
    float h = 0.f;
#pragma unroll
    for (int c = 0; c < NCH; c++) {
        size_t o = (size_t)c * NREC + t;
        float P = Pbuf[o];
        float E = Ebuf[o];
        Ebuf[o] = h;
        h = fmaf(P, h, E);
    }
}

// ---------------------------------------------------------------- k_scanB
__global__ __launch_bounds__(256) void k_scanB(const float* __restrict__ dtl,
                                               const float* __restrict__ xdbl,
                                               const float* __restrict__ xic,
                                               const float* __restrict__ A_log,
                                               const float* __restrict__ Dp,
                                               const float* __restrict__ Hbuf,
                                               float* __restrict__ yt0,
                                               float* __restrict__ yt1) {
    __shared__ float Bs[64][64];
    __shared__ float Cs[64][64];
    int bx = blockIdx.x;
    int bk = bx & 7, ch = (bx >> 3) & 15, dpair = bx >> 7;
    int k = bk & 3, b = bk >> 2;
    int tid = threadIdx.x;
    int wid = tid >> 6, lane = tid & 63;
    int sh = wid & 1, dgrp = dpair * 2 + (wid >> 1);
    int d = dgrp * 64 + lane;
    int l0 = ch * CLn;
    const float* xdb = xdbl + (size_t)bk * Ln * 144;
#pragma unroll
    for (int p = 0; p < 4; p++) {
        int f4 = p * 256 + tid;
        int row = f4 >> 4, c4 = f4 & 15;
        *(float4*)&Bs[row][c4 * 4] =
            *(const float4*)&xdb[(size_t)(l0 + row) * 144 + 16 + c4 * 4];
        *(float4*)&Cs[row][c4 * 4] =
            *(const float4*)&xdb[(size_t)(l0 + row) * 144 + 80 + c4 * 4];
    }
    __syncthreads();
    float Aln[32], h[32];
    size_t o0 = (size_t)(((ch * 8 + bk) * 2 + sh) * 32) * DIn + d;
#pragma unroll
    for (int s = 0; s < 32; s++) {
        Aln[s] = -__expf(A_log[(size_t)(k * DIn + d) * DSn + sh * 32 + s]);
        h[s] = Hbuf[o0 + (size_t)s * DIn];
    }
    const float* dtp = dtl + ((size_t)(bk << 10)) * DIn + d;
    const float* xcb = xic + ((size_t)(b << 10)) * DIn + d;
    float Dv = Dp[k * DIn + d];
    float* yts = (sh == 0) ? yt0 : yt1;
#pragma unroll 2
    for (int j = 0; j < CLn; j++) {
        int l = l0 + j;
        float dt = dtp[(size_t)l * DIn];
        float u  = xcb[(size_t)permidx(k, l) * DIn];
        float du = dt * u;
        float yp = (sh == 0) ? u * Dv : 0.f;
#pragma unroll
        for (int s4 = 0; s4 < 8; s4++) {
            float4 bv = *(const float4*)&Bs[j][sh * 32 + s4 * 4];
            float4 cv = *(const float4*)&Cs[j][sh * 32 + s4 * 4];
            h[s4*4+0] = fmaf(h[s4*4+0], __expf(dt * Aln[s4*4+0]), du * bv.x);
            yp = fmaf(h[s4*4+0], cv.x, yp);
            h[s4*4+1] = fmaf(h[s4*4+1], __expf(dt * Aln[s4*4+1]), du * bv.y);
            yp = fmaf(h[s4*4+1], cv.y, yp);
            h[s4*4+2] = fmaf(h[s4*4+2], __expf(dt * Aln[s4*4+2]), du * bv.z);
            yp = fmaf(h[s4*4+2], cv.z, yp);
            h[s4*4+3] = fmaf(h[s4*4+3], __expf(dt * Aln[s4*4+3]), du * bv.w);
            yp = fmaf(h[s4*4+3], cv.w, yp);
        }
        yts[((size_t)(bk << 10) + l) * DIn + d] = yp;
    }
}

// ---------------------------------------------------------------- k_comb
// ycomb[b,l,:] = bf16( (LN_512(sum of 4 dirs)*ln_w + ln_b) * silu(z) )
__global__ __launch_bounds__(512) void k_comb(const float* __restrict__ yt0,
                                              const float* __restrict__ yt1,
                                              const float* __restrict__ xz,
                                              const float* __restrict__ ln_w,
                                              const float* __restrict__ ln_b,
                                              bf16* __restrict__ yc) {
    int b = blockIdx.y, l = blockIdx.x, d = threadIdx.x;
    int tpl = ((l & 31) << 5) | (l >> 5);
    int b4 = b << 2;
    size_t i0 = ((size_t)((b4 + 0) << 10) + l) * DIn + d;
    size_t i1 = ((size_t)((b4 + 1) << 10) + tpl) * DIn + d;
    size_t i2 = ((size_t)((b4 + 2) << 10) + (Ln - 1 - l)) * DIn + d;
    size_t i3 = ((size_t)((b4 + 3) << 10) + (Ln - 1 - tpl)) * DIn + d;
    float v = yt0[i0] + yt1[i0] + yt0[i1] + yt1[i1]
            + yt0[i2] + yt1[i2] + yt0[i3] + yt1[i3];
    float s1 = v, s2 = v * v;
#pragma unroll
    for (int o = 32; o > 0; o >>= 1) { s1 += __shfl_xor(s1, o); s2 += __shfl_xor(s2, o); }
    __shared__ float red[16];
    int wid = threadIdx.x >> 6, lane = threadIdx.x & 63;
    if (lane == 0) { red[wid * 2] = s1; red[wid * 2 + 1] = s2; }
    __syncthreads();
    s1 = 0.f; s2 = 0.f;
#pragma unroll
    for (int w = 0; w < 8; w++) { s1 += red[w * 2]; s2 += red[w * 2 + 1]; }
    float mu  = s1 * (1.f / DIn);
    float var = s2 * (1.f / DIn) - mu * mu;
    float r   = rsqrtf(var + 1e-6f);
    float z   = xz[((size_t)(b << 10) + l) * 1024 + DIn + d];
    yc[((size_t)(b << 10) + l) * DIn + d] =
        __float2bfloat16(((v - mu) * r * ln_w[d] + ln_b[d]) * silu_f(z));
}

// ---------------------------------------------------------------- launch
extern "C" void kernel_launch(void* const* d_in, const int* in_sizes, int n_in,
                              void* d_out, int out_size, void* d_ws, size_t ws_size,
                              hipStream_t stream) {
    const float* x      = (const float*)d_in[0];
    const float* c      = (const float*)d_in[1];
    const float* W_ada  = (const float*)d_in[2];
    const float* b_ada  = (const float*)d_in[3];
    const float* W_in   = (const float*)d_in[4];
    const float* b_in   = (const float*)d_in[5];
    const float* conv_w = (const float*)d_in[6];
    const float* conv_b = (const float*)d_in[7];
    const float* W_xp   = (const float*)d_in[8];
    const float* W_dtw  = (const float*)d_in[9];
    const float* dt_b   = (const float*)d_in[10];
    const float* A_log  = (const float*)d_in[11];
    const float* Dp     = (const float*)d_in[12];
    const float* ln_w   = (const float*)d_in[13];
    const float* ln_b   = (const float*)d_in[14];
    const float* W_out  = (const float*)d_in[15];
    const float* b_out  = (const float*)d_in[16];
    const float* W_fc1  = (const float*)d_in[17];
    const float* b_fc1  = (const float*)d_in[18];
    const float* W_fc2  = (const float*)d_in[19];
    const float* b_fc2  = (const float*)d_in[20];
    float* out = (float*)d_out;
    float* ws  = (float*)d_ws;

    // workspace layout (float slots); bf16 arrays use 2 els/slot
    float* mod   = ws;                   // 3072
    float* xz    = mod + 3072;           // 2097152
    float* xic   = xz + 2097152;         // 1048576
    bf16*  xich  = (bf16*)(xic + 1048576);      // 524288 slots
    float* xdbl  = xic + 1048576 + 524288;      // 1179648
    float* dtl   = xdbl + 1179648;       // 4194304
    float* Ebuf  = dtl + 4194304;        // 4194304 (doubles as Hbuf)
    float* yt0   = Ebuf + 4194304;       // 4194304
    float* yt1   = yt0 + 4194304;        // 4194304
    bf16*  ycomb = (bf16*)(yt1 + 4194304);      // 524288 slots
    float* x1    = yt1 + 4194304 + 524288;      // 524288
    bf16*  Wti   = (bf16*)(x1 + 524288);        // 131072 slots (1024x256)
    bf16*  Wto   = Wti + 262144;         // 65536 slots  (256x512)
    bf16*  Wt1   = Wto + 131072;         // 131072 slots (1024x256)
    bf16*  Wt2   = Wt1 + 262144;         // 131072 slots (256x1024)
    // aliases (temporally disjoint)
    bf16*  hmod  = (bf16*)yt0;           // dead before scanB writes yt0
    bf16*  m0    = (bf16*)Ebuf;          // dead after scanB
    bf16*  m1    = (bf16*)dtl;           // dead after scanB
    bf16*  Wtx   = (bf16*)yt1;           // dead before scanA writes Pbuf
    float* Pbuf  = yt1;                  // dead before scanB writes yt1
    float* pred  = yt0;                  // split-K partials, after k_comb

    // weight transpose+convert (bf16 [N][K])
    k_wt<<<dim3(32, 8), 256, 0, stream>>>(W_in, Wti, 256, 1024, 1024);
    k_wt<<<dim3(8, 16), 256, 0, stream>>>(W_out, Wto, 512, 256, 256);
    k_wt<<<dim3(32, 8), 256, 0, stream>>>(W_fc1, Wt1, 256, 1024, 1024);
    k_wt<<<dim3(8, 32), 256, 0, stream>>>(W_fc2, Wt2, 1024, 256, 256);
    k_wt<<<dim3(6, 16, 4), 256, 0, stream>>>(W_xp, Wtx, 512, 144, 192);

    k_mod<<<dim3(6, Bn), 256, 0, stream>>>(c, W_ada, b_ada, mod);
    k_ln_mod<<<dim3(Ln, Bn), 256, 0, stream>>>(x, mod, 0, 256, hmod);
    gemm_bf<0><<<dim3(16, 32, 1), 256, 0, stream>>>(hmod, Wti, b_in, xz, nullptr,
                                                    1024, 256, 256);
    k_conv<<<dim3(4096), 256, 0, stream>>>(xz, conv_w, conv_b, xic, xich);
    gemm_xdbl_bf<<<dim3(3, 16, 8), 256, 0, stream>>>(xich, Wtx, xdbl);
    k_dt<<<dim3(16, 8, Bn * Kn), 256, 0, stream>>>(xdbl, W_dtw, dt_b, dtl);
    k_scanA<<<dim3(512), 256, 0, stream>>>(dtl, xdbl, xic, A_log, Pbuf, Ebuf);
    k_scan2<<<dim3(1024), 256, 0, stream>>>(Pbuf, Ebuf);
    k_scanB<<<dim3(512), 256, 0, stream>>>(dtl, xdbl, xic, A_log, Dp, Ebuf, yt0, yt1);
    k_comb<<<dim3(Ln, Bn), 512, 0, stream>>>(yt0, yt1, xz, ln_w, ln_b, ycomb);
    gemm_bf<-1><<<dim3(4, 32, 4), 256, 0, stream>>>(ycomb, Wto, nullptr, pred, nullptr,
                                                    256, 512, 128);
    k_redep<<<dim3(2048), 256, 0, stream>>>(pred, 4, b_out, x, mod, 512, x1);
    k_ln_mod<<<dim3(Ln, Bn), 256, 0, stream>>>(x1, mod, 768, 1024, m0);
    gemm_bf<1><<<dim3(16, 32, 1), 256, 0, stream>>>(m0, Wt1, b_fc1, nullptr, m1,
                                                    1024, 256, 256);
    gemm_bf<-1><<<dim3(4, 32, 8), 256, 0, stream>>>(m1, Wt2, nullptr, pred, nullptr,
                                                    256, 1024, 128);
    k_redep<<<dim3(2048), 256, 0, stream>>>(pred, 8, b_fc2, x1, mod, 1280, out);
}